// Round 1
// baseline (240.495 us; speedup 1.0000x reference)
//
#include <hip/hip_runtime.h>
#include <stdint.h>

typedef __attribute__((ext_vector_type(8))) short  short8;   // 8 bf16 = 4 VGPR (MFMA A/B frag)
typedef __attribute__((ext_vector_type(4))) short  short4v;
typedef __attribute__((ext_vector_type(4))) float  float4v;  // MFMA C/D frag

#define MFMA16(a, b, c) __builtin_amdgcn_mfma_f32_16x16x32_bf16((a), (b), (c), 0, 0, 0)

// fp32 -> bf16 round-to-nearest-even on raw bits (finite inputs only)
static __device__ __forceinline__ short f2bf(float f) {
  uint32_t u = __float_as_uint(f);
  uint32_t r = (u + 0x7FFFu + ((u >> 16) & 1u)) >> 16;
  return (short)(r & 0xFFFFu);
}

#define S_LEN  4096
#define NBATCH 4
#define EMB    1024
#define DD     64
#define NROWS  (NBATCH * S_LEN)  // 16384
#define L2E    1.4426950408889634f
#define NEG_BIG (-1e30f)

// ======================= Kernel 1: fused QKV projection =======================
// q = x*Wq^T, k = x*Wk^T stored row-major bf16 [16384][64];
// v stored TRANSPOSED: Vt[b][d][s] bf16 (computed as Wv * x^T so the epilogue
// store is 16-consecutive-bf16 along s, and the attention PV B-frag is a
// contiguous 16B load).
#define BK   32
#define LSTR 40  // 32 + 8 pad (shorts): 80B row stride, 16B-aligned, 2-way banks only

__global__ __launch_bounds__(256, 1) void qkv_kernel(
    const float* __restrict__ x, const float* __restrict__ Wq,
    const float* __restrict__ Wk, const float* __restrict__ Wv,
    short* __restrict__ Qb, short* __restrict__ Kb, short* __restrict__ Vt) {
  __shared__ short lds[2][4][64 * LSTR];  // [buf][x,wq,wk,wv][row*LSTR + k]

  const int tid  = threadIdx.x;
  const int w    = tid >> 6;
  const int lane = tid & 63;
  const int ln   = lane & 15;
  const int quad = lane >> 4;
  const int s0   = blockIdx.x * 64;

  // staging map: per array 512 float4 (64 rows x 8 float4); 2 per thread
  const int i0 = tid, i1 = tid + 256;
  const int r0 = i0 >> 3, c0 = (i0 & 7) * 4;
  const int r1 = i1 >> 3, c1 = (i1 & 7) * 4;

  float4v accQ[4], accK[4], accV[4];
  const float4v zz = {0.f, 0.f, 0.f, 0.f};
#pragma unroll
  for (int n = 0; n < 4; ++n) { accQ[n] = zz; accK[n] = zz; accV[n] = zz; }

  float4v rg[8];

#define LOAD_STAGE(k0) do {                                                \
    rg[0] = *(const float4v*)(x  + (s0 + r0) * EMB + (k0) + c0);           \
    rg[1] = *(const float4v*)(x  + (s0 + r1) * EMB + (k0) + c1);           \
    rg[2] = *(const float4v*)(Wq + r0 * EMB + (k0) + c0);                  \
    rg[3] = *(const float4v*)(Wq + r1 * EMB + (k0) + c1);                  \
    rg[4] = *(const float4v*)(Wk + r0 * EMB + (k0) + c0);                  \
    rg[5] = *(const float4v*)(Wk + r1 * EMB + (k0) + c1);                  \
    rg[6] = *(const float4v*)(Wv + r0 * EMB + (k0) + c0);                  \
    rg[7] = *(const float4v*)(Wv + r1 * EMB + (k0) + c1);                  \
  } while (0)

#define WRITE_STAGE(BUF) do {                                              \
    _Pragma("unroll")                                                      \
    for (int a = 0; a < 4; ++a) {                                          \
      float4v v0 = rg[a * 2 + 0];                                          \
      float4v v1 = rg[a * 2 + 1];                                          \
      short4v t0 = {f2bf(v0[0]), f2bf(v0[1]), f2bf(v0[2]), f2bf(v0[3])};   \
      short4v t1 = {f2bf(v1[0]), f2bf(v1[1]), f2bf(v1[2]), f2bf(v1[3])};   \
      *(short4v*)&lds[BUF][a][r0 * LSTR + c0] = t0;                        \
      *(short4v*)&lds[BUF][a][r1 * LSTR + c1] = t1;                        \
    }                                                                      \
  } while (0)

#define COMPUTE(BUF) do {                                                  \
    const int fo = quad * 8;                                               \
    short8 a_x  = *(const short8*)&lds[BUF][0][(w * 16 + ln) * LSTR + fo]; \
    short8 a_wv = *(const short8*)&lds[BUF][3][(w * 16 + ln) * LSTR + fo]; \
    _Pragma("unroll")                                                      \
    for (int n = 0; n < 4; ++n) {                                          \
      short8 b_q = *(const short8*)&lds[BUF][1][(n * 16 + ln) * LSTR + fo];\
      short8 b_k = *(const short8*)&lds[BUF][2][(n * 16 + ln) * LSTR + fo];\
      short8 b_x = *(const short8*)&lds[BUF][0][(n * 16 + ln) * LSTR + fo];\
      accQ[n] = MFMA16(a_x,  b_q, accQ[n]);                                \
      accK[n] = MFMA16(a_x,  b_k, accK[n]);                                \
      accV[n] = MFMA16(a_wv, b_x, accV[n]);                                \
    }                                                                      \
  } while (0)

  LOAD_STAGE(0);
  WRITE_STAGE(0);
  __syncthreads();

  int bufi = 0;
#pragma unroll 2
  for (int st = 0; st < 32; ++st) {
    if (st + 1 < 32) LOAD_STAGE((st + 1) * BK);  // global loads overlap compute
    COMPUTE(bufi);
    if (st + 1 < 32) WRITE_STAGE(bufi ^ 1);
    __syncthreads();
    bufi ^= 1;
  }

  // epilogue: C-layout row = quad*4+r, col = ln
#pragma unroll
  for (int n = 0; n < 4; ++n) {
#pragma unroll
    for (int r = 0; r < 4; ++r) {
      const int row = s0 + w * 16 + quad * 4 + r;  // x row (Q/K)
      const int col = n * 16 + ln;                 // d
      Qb[row * DD + col] = f2bf(accQ[n][r]);
      Kb[row * DD + col] = f2bf(accK[n][r]);
      const int d  = w * 16 + quad * 4 + r;        // Vt: row = d, col = s
      const int sg = s0 + n * 16 + ln;
      Vt[((sg >> 12) * DD + d) * S_LEN + (sg & (S_LEN - 1))] = f2bf(accV[n][r]);
    }
  }
#undef LOAD_STAGE
#undef WRITE_STAGE
#undef COMPUTE
}

// ======================= Kernel 2: causal flash attention =======================
// One wave (64 thr) per 16 query rows; 1024 workgroups (4/CU), even/odd band
// interleave for causal load balance. KV tile = 32; K/V frags loaded straight
// from L2-hot global, prefetched one tile ahead. P transposed C->A layout via
// per-wave LDS round-trip (m120 pattern).
#define PSTR 40  // P row stride in shorts (32 + 8): 80B, 16B-aligned b128 reads

__global__ __launch_bounds__(64, 1) void attn_kernel(
    const short* __restrict__ Qb, const short* __restrict__ Kb,
    const short* __restrict__ Vt, float* __restrict__ out) {
  __shared__ short pbuf[16 * PSTR];

  const int tid  = threadIdx.x;
  const int ln   = tid & 15;
  const int quad = tid >> 4;
  const int g    = blockIdx.x;
  const int b    = g >> 8;        // batch
  const int u    = g & 255;
  const int band = (u & 1) ? (255 - (u >> 1)) : (u >> 1);  // long bands early
  const int qb   = band * 16;     // in-batch query row base
  const int qg0  = b * S_LEN + qb;

  // Q A-frags: A[m=ln][k=quad*8+j], two 32-wide k-steps over D=64
  const short8 aQ0 = *(const short8*)(Qb + (qg0 + ln) * DD + quad * 8);
  const short8 aQ1 = *(const short8*)(Qb + (qg0 + ln) * DD + 32 + quad * 8);

  const short* Kbase = Kb + b * S_LEN * DD;
  const short* Vbase = Vt + b * DD * S_LEN;

  const float4v zz = {0.f, 0.f, 0.f, 0.f};
  float4v o0 = zz, o1 = zz, o2 = zz, o3 = zz;
  float mm[4], ll[4];
#pragma unroll
  for (int r = 0; r < 4; ++r) { mm[r] = NEG_BIG; ll[r] = 0.f; }

  const int ntile = (qb + 47) >> 5;  // kv tiles of 32 covering 0..qb+15

  // current-tile frags (tile 0)
  short8 cK00 = *(const short8*)(Kbase + (0 + ln) * DD + quad * 8);
  short8 cK01 = *(const short8*)(Kbase + (0 + ln) * DD + 32 + quad * 8);
  short8 cK10 = *(const short8*)(Kbase + (16 + ln) * DD + quad * 8);
  short8 cK11 = *(const short8*)(Kbase + (16 + ln) * DD + 32 + quad * 8);
  short8 cV0  = *(const short8*)(Vbase + (0  + ln) * S_LEN + quad * 8);
  short8 cV1  = *(const short8*)(Vbase + (16 + ln) * S_LEN + quad * 8);
  short8 cV2  = *(const short8*)(Vbase + (32 + ln) * S_LEN + quad * 8);
  short8 cV3  = *(const short8*)(Vbase + (48 + ln) * S_LEN + quad * 8);

  for (int it = 0; it < ntile; ++it) {
    const int kv0 = it * 32;
    const int kvn = (it + 1 < ntile) ? kv0 + 32 : 0;  // dummy-but-in-bounds on last
    // prefetch next tile (independent of this tile's compute)
    short8 nK00 = *(const short8*)(Kbase + (kvn + ln) * DD + quad * 8);
    short8 nK01 = *(const short8*)(Kbase + (kvn + ln) * DD + 32 + quad * 8);
    short8 nK10 = *(const short8*)(Kbase + (kvn + 16 + ln) * DD + quad * 8);
    short8 nK11 = *(const short8*)(Kbase + (kvn + 16 + ln) * DD + 32 + quad * 8);
    short8 nV0  = *(const short8*)(Vbase + (0  + ln) * S_LEN + kvn + quad * 8);
    short8 nV1  = *(const short8*)(Vbase + (16 + ln) * S_LEN + kvn + quad * 8);
    short8 nV2  = *(const short8*)(Vbase + (32 + ln) * S_LEN + kvn + quad * 8);
    short8 nV3  = *(const short8*)(Vbase + (48 + ln) * S_LEN + kvn + quad * 8);

    // S = Q K^T : C[row=quad*4+r][col=ln], col tiles c=0,1 (kv0+c*16+ln)
    float4v s0 = zz, s1 = zz;
    s0 = MFMA16(aQ0, cK00, s0);
    s0 = MFMA16(aQ1, cK01, s0);
    s1 = MFMA16(aQ0, cK10, s1);
    s1 = MFMA16(aQ1, cK11, s1);

    const bool needmask = (kv0 + 31) > qb;
    float p0[4], p1[4], al[4];
#pragma unroll
    for (int r = 0; r < 4; ++r) {
      float v0 = s0[r] * 0.125f;  // 1/sqrt(64)
      float v1 = s1[r] * 0.125f;
      if (needmask) {
        const int rowq = qb + quad * 4 + r;
        if (kv0 + ln > rowq)      v0 = NEG_BIG;
        if (kv0 + 16 + ln > rowq) v1 = NEG_BIG;
      }
      float t = fmaxf(v0, v1);
      t = fmaxf(t, __shfl_xor(t, 1));
      t = fmaxf(t, __shfl_xor(t, 2));
      t = fmaxf(t, __shfl_xor(t, 4));
      t = fmaxf(t, __shfl_xor(t, 8));
      const float mn = fmaxf(mm[r], t);
      const float a  = exp2f((mm[r] - mn) * L2E);
      p0[r] = exp2f((v0 - mn) * L2E);
      p1[r] = exp2f((v1 - mn) * L2E);
      float sum = p0[r] + p1[r];
      sum += __shfl_xor(sum, 1);
      sum += __shfl_xor(sum, 2);
      sum += __shfl_xor(sum, 4);
      sum += __shfl_xor(sum, 8);
      ll[r] = ll[r] * a + sum;
      mm[r] = mn;
      al[r] = a;
    }
#pragma unroll
    for (int r = 0; r < 4; ++r) {
      o0[r] *= al[r]; o1[r] *= al[r]; o2[r] *= al[r]; o3[r] *= al[r];
    }
    // P: C-layout -> row-major LDS [16][32] (padded) -> A-frag readback
#pragma unroll
    for (int r = 0; r < 4; ++r) {
      pbuf[(quad * 4 + r) * PSTR + ln]      = f2bf(p0[r]);
      pbuf[(quad * 4 + r) * PSTR + 16 + ln] = f2bf(p1[r]);
    }
    asm volatile("s_waitcnt lgkmcnt(0)" ::: "memory");  // wave-internal LDS drain
    const short8 aP = *(const short8*)&pbuf[ln * PSTR + quad * 8];
    o0 = MFMA16(aP, cV0, o0);
    o1 = MFMA16(aP, cV1, o1);
    o2 = MFMA16(aP, cV2, o2);
    o3 = MFMA16(aP, cV3, o3);

    cK00 = nK00; cK01 = nK01; cK10 = nK10; cK11 = nK11;
    cV0 = nV0; cV1 = nV1; cV2 = nV2; cV3 = nV3;
  }

#pragma unroll
  for (int r = 0; r < 4; ++r) {
    const float inv = 1.0f / ll[r];
    const int row = qg0 + quad * 4 + r;
    out[row * DD + 0  + ln] = o0[r] * inv;
    out[row * DD + 16 + ln] = o1[r] * inv;
    out[row * DD + 32 + ln] = o2[r] * inv;
    out[row * DD + 48 + ln] = o3[r] * inv;
  }
}

extern "C" void kernel_launch(void* const* d_in, const int* in_sizes, int n_in,
                              void* d_out, int out_size, void* d_ws, size_t ws_size,
                              hipStream_t stream) {
  const float* x  = (const float*)d_in[0];
  const float* Wq = (const float*)d_in[1];
  const float* Wk = (const float*)d_in[2];
  const float* Wv = (const float*)d_in[3];

  // workspace: Qb (2MB) | Kb (2MB) | Vt (2MB), all bf16-as-short
  short* Qb = (short*)d_ws;
  short* Kb = Qb + (size_t)NROWS * DD;
  short* Vt = Kb + (size_t)NROWS * DD;

  qkv_kernel<<<dim3(NROWS / 64), dim3(256), 0, stream>>>(x, Wq, Wk, Wv, Qb, Kb, Vt);
  attn_kernel<<<dim3(NBATCH * 256), dim3(64), 0, stream>>>(Qb, Kb, Vt, (float*)d_out);
}